// Round 12
// baseline (274.917 us; speedup 1.0000x reference)
//
#include <hip/hip_runtime.h>
#include <hip/hip_fp16.h>

// RGCN R22: remembered-rank placement -- halve LDS atomics in group & sortb.
// R21 postmortem: sortb 53us leader; with R19's measured ~3.7cy/lane LDS
// atomic RMW, its 2 atomics/record (hist + place) are ~25-35us of the 53.
// The place atomic is redundant: phase A's atomicAdd RETURN VALUE is the
// record's rank within its bin. R22: keep ranks in VGPRs (packed bytes);
// placement = base + exclusive_prefix[bin] + rank (plain LDS byte read).
// hist stays EXCLUSIVE prefix; phase C cnt = excl[bi+1]-excl[bi] (or hh at
// rel=89). Same trick in group_k (rank packed into bkt[k] high bits).

#define NREL   90
#define BSH    7
#define BNODES 128       // nodes per bucket
#define NBINS  1024      // gcount table size
#define NB2    784       // scan bins (49 lanes x 16); buckets <= 782
#define GCH    8704      // edges per chunk = 512*17
#define KPT    17        // edges per thread in group_k
#define SPK    11056     // s_pack slots >= 8704 + 782*3 = 11050 hard max
#define CAPB   10496     // per-bucket region capacity; fill mean 9300 + 12s
#define NV4    6         // ceil(CAPB/4/512) uint4 loads per thread in sortb
#define STAGE  9088      // sortb stage capacity; valid cnt mean 8192 + 9.9s
#define LPD    16        // dsts per block in layer kernels (16 lanes each)
#define SENT   0xFFFFFFFFu

__device__ __forceinline__ float frelu(float v) { return v > 0.0f ? v : 0.0f; }

// ---------- K1: fused pad-x + single-read grouping, padded reservation ----------
// record = src | rel<<17 | dstLocal<<24 ; sentinel unreachable (rel <= 89).
__launch_bounds__(512)
__global__ void group_k(const float* __restrict__ x, float4* __restrict__ x4,
                        int N, int gNp,
                        const int* __restrict__ src, const int* __restrict__ dst,
                        const int* __restrict__ et, int* __restrict__ gcount,
                        unsigned* __restrict__ regions, int E) {
    int tid = threadIdx.x;
    if (blockIdx.x < gNp) {           // pad role
        int i = blockIdx.x * 512 + tid;
        if (i < N) x4[i] = make_float4(x[3 * i], x[3 * i + 1], x[3 * i + 2], 0.0f);
        return;
    }
    __shared__ int s_cur[NB2];        // 4-aligned starts (read-only in place)
    __shared__ int s_pend[NB2];       // hist, then padded end (next start)
    __shared__ int s_off[NB2];        // reserved_base - start (multiple of 4)
    __shared__ unsigned s_pack[SPK];  // 44224 B -> total 53632 B (3 blk/CU)
    int chunk = blockIdx.x - gNp;
    int e0 = chunk * GCH;
    int cnt = min(GCH, E - e0);
    for (int i = tid; i < NB2; i += 512) s_pend[i] = 0;
    __syncthreads();
    // single global read: pack records into VGPRs; hist atomic's OLD VALUE is
    // this record's rank within its (chunk,bucket) run -> pack into bkt high
    // bits (run <= 8704 < 2^16; bucket < 1024; sign test still flags invalid)
    unsigned rec[KPT];
    int bkt[KPT];
#pragma unroll
    for (int k = 0; k < KPT; k++) {
        int q = tid + k * 512;
        if (q < cnt) {
            int e = e0 + q;
            int d = dst[e];
            int b = d >> BSH;
            rec[k] = (unsigned)src[e] | ((unsigned)et[e] << 17) |
                     ((unsigned)(d & (BNODES - 1)) << 24);
            int old = atomicAdd(&s_pend[b], 1);
            bkt[k] = b | (old << 16);
        } else bkt[k] = -1;
    }
    __syncthreads();
    // scan of padded (roundup4) lengths: 49 lanes x 16 bins
    if (tid < 49) {
        int loc[16];
        int s = 0;
        int b0 = tid * 16;
#pragma unroll
        for (int k = 0; k < 16; k++) {
            int plen = (s_pend[b0 + k] + 3) & ~3;
            loc[k] = plen; s += plen;
        }
        int inc = s;
#pragma unroll
        for (int off = 1; off < 64; off <<= 1) {
            int u = __shfl_up(inc, off);
            if (tid >= off) inc += u;
        }
        int run = inc - s;
#pragma unroll
        for (int k = 0; k < 16; k++) {
            s_cur[b0 + k] = run;
            run += loc[k];
            s_pend[b0 + k] = run;     // padded end = next start (monotone)
        }
    }
    __syncthreads();
    int T = s_pend[NB2 - 1];          // total padded slots this chunk
    // reservation (4-aligned) + overflow cleanup
    for (int b = tid; b < NB2; b += 512) {
        int st = s_cur[b];
        int plen = s_pend[b] - st;
        if (plen > 0) {
            int gb = atomicAdd(&gcount[b], plen);
            if (gb + plen <= CAPB) {
                s_off[b] = gb - st;   // multiple of 4
            } else {                  // overflow: drop run, keep region clean
                s_off[b] = 0x40000000;
                unsigned* reg = regions + (size_t)b * CAPB;
                for (int j = min(gb, CAPB); j < CAPB; j++) reg[j] = SENT;
            }
        } else s_off[b] = 0x40000000;
    }
    // sentinel pre-fill of the padded LDS image
    for (int i = tid; i < T; i += 512) s_pack[i] = SENT;
    __syncthreads();
    // place from regs: start + remembered rank (NO atomic)
#pragma unroll
    for (int k = 0; k < KPT; k++) {
        if (bkt[k] >= 0) {
            int b = bkt[k] & 0xFFFF;
            int r = ((unsigned)bkt[k]) >> 16;
            s_pack[s_cur[b] + r] = rec[k];
        }
    }
    __syncthreads();
    // coalesced writeout: each aligned 4-slot group is within one run
    int nv = T >> 2;
    for (int i4 = tid; i4 < nv; i4 += 512) {
        int i = i4 << 2;
        int lo = 0, hi = NB2 - 1;     // first b with s_pend[b] > i
        while (lo < hi) {
            int mid = (lo + hi) >> 1;
            if (s_pend[mid] > i) hi = mid; else lo = mid + 1;
        }
        int loc = s_off[lo] + i;
        if (loc < CAPB) {
            uint4 v = make_uint4(s_pack[i], s_pack[i + 1],
                                 s_pack[i + 2], s_pack[i + 3]);
            *(uint4*)(regions + (size_t)lo * CAPB + loc) = v;
        }
    }
}

// ---------- K2: (dst,rel) counting sort + FUSED LAYER 1, rank-reuse ----------
// phase A: uint4 region read; hist atomic returns per-bin rank (kept packed
// in VGPR bytes). Prefix conversion leaves EXCLUSIVE prefixes in hist8w.
// phase B: pos = base + excl[bin] + rank (LDS byte READ, no atomic).
// phase C: cnt = (rel==89 ? hh[dL] : excl[bi+1]) - excl[bi]; cnt-packed
// record back to stage32 -> linear uint4 writeout; h1 packed 8xfp16.
__launch_bounds__(512)
__global__ void sortb_l1_k(const int* __restrict__ gcount, unsigned* regions,
                           int2* __restrict__ rowseg,
                           const float4* __restrict__ x4, const float* __restrict__ W,
                           const float* __restrict__ root, const float* __restrict__ bias,
                           uint4* __restrict__ h1h, int N) {
    __shared__ unsigned stage32[STAGE];            // 36352 B
    __shared__ unsigned hist8w[BNODES * 90 / 4];   // 11520 B
    __shared__ int hh[BNODES], base_[BNODES];      // 1024 B
    __shared__ float4 w4[NREL * 2];                // 2880 B -> 51776 total
    int tid = threadIdx.x, b = blockIdx.x;
    for (int i = tid; i < BNODES * 90 / 4; i += 512) hist8w[i] = 0u;
    for (int i = tid; i < NREL * 2; i += 512) {
        int r = i >> 1;
        w4[i] = (i & 1) ? make_float4(W[r * 6 + 4], W[r * 6 + 5], 0.f, 0.f)
                        : make_float4(W[r * 6], W[r * 6 + 1], W[r * 6 + 2], W[r * 6 + 3]);
    }
    __syncthreads();
    int fill = gcount[b];
    if (fill > CAPB) fill = CAPB;
    const uint4* reg4 = (const uint4*)(regions + (size_t)b * CAPB);
    int nv = fill >> 2;               // fill is a multiple of 4
    // phase A: all 6 uint4 loads issued first (6-deep MLP), then u8 hist;
    // remember each record's per-bin rank (atomic old value), packed 4/word
    uint4 rec4[NV4];
    unsigned rnk[NV4];
#pragma unroll
    for (int k = 0; k < NV4; k++) {
        int i4 = tid + k * 512;
        rec4[k] = (i4 < nv) ? reg4[i4] : make_uint4(SENT, SENT, SENT, SENT);
        rnk[k] = 0u;
    }
#define HIST1(P, R, SH) if ((P) != SENT) { \
        unsigned bi_ = ((P) >> 24) * 90u + (((P) >> 17) & 127u); \
        unsigned sh_ = (bi_ & 3) << 3; \
        unsigned old_ = atomicAdd(&hist8w[bi_ >> 2], 1u << sh_); \
        (R) |= ((old_ >> sh_) & 0xFFu) << (SH); }
#pragma unroll
    for (int k = 0; k < NV4; k++) {
        HIST1(rec4[k].x, rnk[k], 0); HIST1(rec4[k].y, rnk[k], 8);
        HIST1(rec4[k].z, rnk[k], 16); HIST1(rec4[k].w, rnk[k], 24);
    }
    __syncthreads();
    // in-place rel-prefix conversion: 128 threads, one 90-byte dst row each;
    // hist8w bytes become EXCLUSIVE prefixes (and stay that way)
    unsigned char* h8w = (unsigned char*)hist8w;
    if (tid < BNODES) {
        unsigned run = 0;
        int rbase = tid * 90;
        for (int k = 0; k < 90; k++) {
            unsigned c = h8w[rbase + k];
            h8w[rbase + k] = (unsigned char)run;
            run += c;
        }
        hh[tid] = (int)run;
    }
    __syncthreads();
    if (tid < 64) {       // exclusive scan of 128 bins, 2/lane
        int c0 = hh[2 * tid], c1 = hh[2 * tid + 1];
        int s = c0 + c1;
        int inc = s;
#pragma unroll
        for (int off = 1; off < 64; off <<= 1) {
            int u = __shfl_up(inc, off);
            if (tid >= off) inc += u;
        }
        int run2 = inc - s;
        base_[2 * tid] = run2;
        base_[2 * tid + 1] = run2 + c0;
    }
    __syncthreads();
    int cntv = base_[BNODES - 1] + hh[BNODES - 1];   // total valid records
    if (cntv > STAGE) cntv = STAGE;                  // safety clamp
    if (tid < BNODES) {
        int d = (b << BSH) + tid;
        if (d < N) {
            int beg = base_[tid];
            int end = beg + hh[tid];
            if (beg > cntv) beg = cntv;
            if (end > cntv) end = cntv;
            rowseg[d] = make_int2(b * CAPB + beg, b * CAPB + end);
        }
    }
    // phase B: place via base + exclusive prefix + remembered rank (no atomic)
    const unsigned char* h8c = (const unsigned char*)hist8w;
#define PLACE1(P, R, SH) if ((P) != SENT) { \
        unsigned dL_ = (P) >> 24; \
        unsigned bi_ = dL_ * 90u + (((P) >> 17) & 127u); \
        int pos_ = base_[dL_] + (int)h8c[bi_] + (int)(((R) >> (SH)) & 0xFFu); \
        if (pos_ < STAGE) stage32[pos_] = (P); }
#pragma unroll
    for (int k = 0; k < NV4; k++) {
        PLACE1(rec4[k].x, rnk[k], 0); PLACE1(rec4[k].y, rnk[k], 8);
        PLACE1(rec4[k].z, rnk[k], 16); PLACE1(rec4[k].w, rnk[k], 24);
    }
    __syncthreads();
    // phase C (fused L1): 32 groups of 16 lanes, 4 dsts each; cnt from
    // exclusive-prefix differences; cnt-packed record back to stage32.
    const unsigned char* h8 = (const unsigned char*)hist8w;
    int grp = tid >> 4, l16 = tid & 15;
#pragma unroll
    for (int rd = 0; rd < 4; rd++) {
        int dL = grp + rd * 32;
        int segb = base_[dL];
        int sege = segb + hh[dL];
        if (sege > cntv) sege = cntv;
        float a0 = 0, a1 = 0, a2 = 0, a3 = 0, a4 = 0, a5 = 0;
        for (int q = segb + l16; q < sege; q += 16) {
            unsigned p = stage32[q];
            unsigned rel = (p >> 17) & 127u;
            unsigned bi = dL * 90u + rel;
            unsigned c = ((rel == 89u) ? (unsigned)hh[dL] : (unsigned)h8[bi + 1])
                         - (unsigned)h8[bi];
            stage32[q] = (p & 0x00FFFFFFu) | (c << 24);
            float r = __builtin_amdgcn_rcpf((float)c);
            float4 xv = x4[p & 0x1FFFFu];
            unsigned rel2 = rel * 2u;
            float4 wa = w4[rel2], wb = w4[rel2 + 1];
            float x0 = xv.x * r, x1 = xv.y * r, x2 = xv.z * r;
            a0 += x0 * wa.x; a1 += x0 * wa.y;
            a2 += x1 * wa.z; a3 += x1 * wa.w;
            a4 += x2 * wb.x; a5 += x2 * wb.y;
        }
#pragma unroll
        for (int off = 8; off > 0; off >>= 1) {
            a0 += __shfl_down(a0, off); a1 += __shfl_down(a1, off); a2 += __shfl_down(a2, off);
            a3 += __shfl_down(a3, off); a4 += __shfl_down(a4, off); a5 += __shfl_down(a5, off);
        }
        if (l16 == 0) {
            int d = (b << BSH) + dL;
            if (d < N) {
                float4 xv = x4[d];
                float o[6] = {a0, a1, a2, a3, a4, a5};
#pragma unroll
                for (int j = 0; j < 6; j++)
                    o[j] = frelu(o[j] + xv.x * root[j] + xv.y * root[6 + j] +
                                 xv.z * root[12 + j] + bias[j]);
                __half2 p01 = __floats2half2_rn(o[0], o[1]);
                __half2 p23 = __floats2half2_rn(o[2], o[3]);
                __half2 p45 = __floats2half2_rn(o[4], o[5]);
                uint4 pk;
                pk.x = *(unsigned*)&p01;
                pk.y = *(unsigned*)&p23;
                pk.z = *(unsigned*)&p45;
                pk.w = 0u;
                h1h[d] = pk;
            }
        }
    }
    __syncthreads();
    // linear coalesced writeout of the sorted, cnt-packed records
    unsigned* regw = regions + (size_t)b * CAPB;
    int nv2 = (cntv + 3) >> 2;
    for (int i4 = tid; i4 < nv2; i4 += 512) {
        int i = i4 << 2;
        uint4 v;
        v.x = stage32[i];
        v.y = (i + 1 < cntv) ? stage32[i + 1] : SENT;
        v.z = (i + 2 < cntv) ? stage32[i + 2] : SENT;
        v.w = (i + 3 < cntv) ? stage32[i + 3] : SENT;
        *(uint4*)(regw + i) = v;
    }
}

// ---------- L2: predicated 4-unroll, SINGLE fp16 gather per edge ----------
__launch_bounds__(256)
__global__ void l2_g(const int2* __restrict__ rowseg, const unsigned* __restrict__ sorted,
                     const uint4* __restrict__ h1h, const float* __restrict__ W,
                     const float* __restrict__ root, const float* __restrict__ bias,
                     float4* __restrict__ h2p, int N) {
    __shared__ float4 w4[NREL * 2];
    for (int i = threadIdx.x; i < NREL * 2; i += 256) {
        int r = i >> 1;
        w4[i] = (i & 1) ? make_float4(W[r * 6 + 4], W[r * 6 + 5], 0.f, 0.f)
                        : make_float4(W[r * 6], W[r * 6 + 1], W[r * 6 + 2], W[r * 6 + 3]);
    }
    __syncthreads();
    int grp = threadIdx.x >> 4, l16 = threadIdx.x & 15;
    int d = blockIdx.x * LPD + grp;
    if (d >= N) return;
    int2 sg = rowseg[d];
    int beg = sg.x, end = sg.y;
    float a0 = 0, a1 = 0, a2 = 0;
    for (int i0 = beg + l16; i0 < end; i0 += 64) {
        unsigned p[4];
        float sc[4];
        uint4 hv[4];
#pragma unroll
        for (int k = 0; k < 4; k++) {       // predicated record loads
            int i = i0 + k * 16;
            int ic = i < end ? i : end - 1;
            p[k] = sorted[ic];
            sc[k] = i < end ? 1.0f : 0.0f;
        }
#pragma unroll
        for (int k = 0; k < 4; k++)         // 4 independent 16B gathers in flight
            hv[k] = h1h[p[k] & 0x1FFFFu];
#pragma unroll
        for (int k = 0; k < 4; k++) {
            unsigned rel2 = ((p[k] >> 17) & 127u) * 2u;
            float4 wa = w4[rel2], wb = w4[rel2 + 1];
            float2 f01 = __half22float2(*(__half2*)&hv[k].x);
            float2 f23 = __half22float2(*(__half2*)&hv[k].y);
            float2 f45 = __half22float2(*(__half2*)&hv[k].z);
            float m0 = f01.x * wa.x + f01.y * wa.y;
            float m1 = f23.x * wa.z + f23.y * wa.w;
            float m2 = f45.x * wb.x + f45.y * wb.y;
            a0 += sc[k] * m0; a1 += sc[k] * m1; a2 += sc[k] * m2;
        }
    }
#pragma unroll
    for (int off = 8; off > 0; off >>= 1) {
        a0 += __shfl_down(a0, off); a1 += __shfl_down(a1, off); a2 += __shfl_down(a2, off);
    }
    if (l16 == 0) {
        uint4 hd = h1h[d];
        float2 g01 = __half22float2(*(__half2*)&hd.x);
        float2 g23 = __half22float2(*(__half2*)&hd.y);
        float2 g45 = __half22float2(*(__half2*)&hd.z);
        float hv6[6] = {g01.x, g01.y, g23.x, g23.y, g45.x, g45.y};
        float o[3] = {a0, a1, a2};
#pragma unroll
        for (int j = 0; j < 3; j++) {
            float v = o[j] + bias[j];
#pragma unroll
            for (int k = 0; k < 6; k++) v += hv6[k] * root[k * 3 + j];
            o[j] = frelu(v);
        }
        h2p[d] = make_float4(o[0], o[1], o[2], 0.0f);
    }
}

// ---------- L3: predicated 4-unroll, mean via packed cnt, fused node + pool ----------
__launch_bounds__(256)
__global__ void l3_g(const int2* __restrict__ rowseg, const unsigned* __restrict__ sorted,
                     const float4* __restrict__ h2p, const float* __restrict__ W,
                     const float* __restrict__ root, const float* __restrict__ bias,
                     const int* __restrict__ batch, float* __restrict__ partials, int N) {
    __shared__ float4 w4[NREL * 2];
    __shared__ float redsm[LPD][8];
    for (int i = threadIdx.x; i < NREL * 2; i += 256) {
        int r = i >> 1;
        w4[i] = (i & 1) ? make_float4(W[r * 6 + 4], W[r * 6 + 5], 0.f, 0.f)
                        : make_float4(W[r * 6], W[r * 6 + 1], W[r * 6 + 2], W[r * 6 + 3]);
    }
    __syncthreads();
    int grp = threadIdx.x >> 4, l16 = threadIdx.x & 15;
    int d = blockIdx.x * LPD + grp;
    float a0 = 0, a1 = 0, a2 = 0, a3 = 0, a4 = 0, a5 = 0;
    if (d < N) {
        int2 sg = rowseg[d];
        int beg = sg.x, end = sg.y;
        for (int i0 = beg + l16; i0 < end; i0 += 64) {
            unsigned p[4];
            float sc[4];
            float4 xv[4];
#pragma unroll
            for (int k = 0; k < 4; k++) {   // predicated record loads
                int i = i0 + k * 16;
                int ic = i < end ? i : end - 1;
                p[k] = sorted[ic];
                sc[k] = i < end ? 1.0f : 0.0f;
            }
#pragma unroll
            for (int k = 0; k < 4; k++) xv[k] = h2p[p[k] & 0x1FFFFu];
#pragma unroll
            for (int k = 0; k < 4; k++) {
                // validity folds into the mean factor: zero r kills all 6 FMAs
                float r = sc[k] * __builtin_amdgcn_rcpf((float)(p[k] >> 24));
                unsigned rel2 = ((p[k] >> 17) & 127u) * 2u;
                float4 wa = w4[rel2], wb = w4[rel2 + 1];
                float x0 = xv[k].x * r, x1 = xv[k].y * r, x2 = xv[k].z * r;
                a0 += x0 * wa.x; a1 += x0 * wa.y;
                a2 += x1 * wa.z; a3 += x1 * wa.w;
                a4 += x2 * wb.x; a5 += x2 * wb.y;
            }
        }
    }
#pragma unroll
    for (int off = 8; off > 0; off >>= 1) {
        a0 += __shfl_down(a0, off); a1 += __shfl_down(a1, off); a2 += __shfl_down(a2, off);
        a3 += __shfl_down(a3, off); a4 += __shfl_down(a4, off); a5 += __shfl_down(a5, off);
    }
    if (l16 == 0) {
        float v[7] = {0, 0, 0, 0, 0, 0, 0};
        if (d < N && batch[d] == 0) {
            float4 xv = h2p[d];
            float o[6] = {a0, a1, a2, a3, a4, a5};
#pragma unroll
            for (int j = 0; j < 6; j++)
                v[j] = frelu(o[j] + xv.x * root[j] + xv.y * root[6 + j] +
                             xv.z * root[12 + j] + bias[j]);
            v[6] = 1.0f;
        }
#pragma unroll
        for (int k = 0; k < 7; k++) redsm[grp][k] = v[k];
    }
    __syncthreads();
    if (threadIdx.x < 7) {
        float t = 0;
#pragma unroll
        for (int g = 0; g < LPD; g++) t += redsm[g][threadIdx.x];
        partials[(size_t)blockIdx.x * 8 + threadIdx.x] = t;
    }
}

// ---------- finalize ----------
__global__ void pool_finalize(const float* __restrict__ partials, int nb,
                              float* __restrict__ out) {
    float v[7] = {0, 0, 0, 0, 0, 0, 0};
    for (int b = threadIdx.x; b < nb; b += blockDim.x) {
#pragma unroll
        for (int k = 0; k < 7; k++) v[k] += partials[(size_t)b * 8 + k];
    }
#pragma unroll
    for (int off = 32; off > 0; off >>= 1) {
#pragma unroll
        for (int k = 0; k < 7; k++) v[k] += __shfl_down(v[k], off);
    }
    __shared__ float sm[16][8];
    int wv = threadIdx.x >> 6, lane = threadIdx.x & 63;
    if (lane == 0) {
#pragma unroll
        for (int k = 0; k < 7; k++) sm[wv][k] = v[k];
    }
    __syncthreads();
    if (threadIdx.x == 0) {
        float t[7] = {0, 0, 0, 0, 0, 0, 0};
        int nw = blockDim.x >> 6;
        for (int q = 0; q < nw; q++) {
#pragma unroll
            for (int k = 0; k < 7; k++) t[k] += sm[q][k];
        }
        float c = t[6] < 1.0f ? 1.0f : t[6];
        float p[6], m = -1e30f;
#pragma unroll
        for (int j = 0; j < 6; j++) { p[j] = t[j] / c; m = fmaxf(m, p[j]); }
        float s = 0.0f;
#pragma unroll
        for (int j = 0; j < 6; j++) s += expf(p[j] - m);
        float lse = m + logf(s);
#pragma unroll
        for (int j = 0; j < 6; j++) out[j] = p[j] - lse;
    }
}

extern "C" void kernel_launch(void* const* d_in, const int* in_sizes, int n_in,
                              void* d_out, int out_size, void* d_ws, size_t ws_size,
                              hipStream_t stream) {
    const float* x     = (const float*)d_in[0];
    const int*   ei    = (const int*)d_in[1];
    const int*   batch = (const int*)d_in[2];
    const int*   etype = (const int*)d_in[3];
    const float* W1    = (const float*)d_in[4];
    const float* root1 = (const float*)d_in[5];
    const float* b1    = (const float*)d_in[6];
    const float* W2    = (const float*)d_in[7];
    const float* root2 = (const float*)d_in[8];
    const float* b2    = (const float*)d_in[9];
    const float* W3    = (const float*)d_in[10];
    const float* root3 = (const float*)d_in[11];
    const float* b3    = (const float*)d_in[12];

    const int N = in_sizes[0] / 3;
    const int E = in_sizes[1] / 2;
    const int* src = ei;
    const int* dst = ei + E;
    const int gG = (E + GCH - 1) / GCH;        // chunks (736 at E=6.4M)
    const int NBUCK = (N + BNODES - 1) >> BSH; // 782
    const int gL = (N + LPD - 1) / LPD;        // 6250

    char* ws = (char*)d_ws;
    size_t off = 0;
    auto alloc = [&](size_t bytes) -> void* {
        void* p = ws + off;
        off += (bytes + 255) & ~(size_t)255;
        return p;
    };
    int*      gcount  = (int*)     alloc(NBINS * sizeof(int));                 // zeroed
    size_t zero_bytes = off;
    unsigned* regions = (unsigned*)alloc((size_t)NBUCK * CAPB * sizeof(unsigned)); // 32.8MB
    int2*     rowseg  = (int2*)    alloc((size_t)N * sizeof(int2));            // 0.8MB
    float4*   x4      = (float4*)  alloc((size_t)N * sizeof(float4));          // 1.6MB
    uint4*    h1h     = (uint4*)   alloc((size_t)N * sizeof(uint4));           // 1.6MB
    float4*   h2p     = (float4*)  alloc((size_t)N * sizeof(float4));          // 1.6MB
    float*    partials = (float*)  alloc((size_t)gL * 8 * sizeof(float));
    // total ~39MB

    hipMemsetAsync(d_ws, 0, zero_bytes, stream);

    const int gNp = (N + 511) / 512;

    group_k<<<gNp + gG, 512, 0, stream>>>(x, x4, N, gNp, src, dst, etype,
                                          gcount, regions, E);
    sortb_l1_k<<<NBUCK, 512, 0, stream>>>(gcount, regions, rowseg,
                                          x4, W1, root1, b1, h1h, N);
    l2_g<<<gL, 256, 0, stream>>>(rowseg, regions, h1h, W2, root2, b2, h2p, N);
    l3_g<<<gL, 256, 0, stream>>>(rowseg, regions, h2p, W3, root3, b3, batch, partials, N);
    pool_finalize<<<1, 1024, 0, stream>>>(partials, gL, (float*)d_out);
}